// Round 8
// baseline (377.208 us; speedup 1.0000x reference)
//
#include <hip/hip_runtime.h>

#define IMG_H 512
#define IMG_W 512
#define NPLANES 24          // N*C = 8*3
#define ROWS_PER_BLK 16     // output rows per block
#define NROWS 26            // staged rows per block (16 + 10 halo)
#define NSLOTS 13           // 2 rows per slot
#define NBLOCKS (32 * 24)
#define TOTAL_PIX 6291456.0f // 8*3*512*512

typedef float f32x2 __attribute__((ext_vector_type(2)));

// Gaussian window, sigma=1.5, K=11, normalized (matches jnp reference ~1e-7)
constexpr float GWc[11] = {
    0.00102838f, 0.00759876f, 0.03600050f, 0.10935817f, 0.21300535f,
    0.26601172f, 0.21300535f, 0.10935817f, 0.03600050f, 0.00759876f,
    0.00102838f};

// Round 8. Evidence so far:
//  - barrier'd structure (R0-R3): spill-safe (44-52 VGPR), ~74us wall,
//    VALU-busy only ~27-39us. Stall: loads issued BEFORE __syncthreads get
//    drained by its implicit s_waitcnt vmcnt(0) -> full latency per slot.
//  - barrier-free unrolled (R5/R7): scheduler hoists loads freely ->
//    live-range explosion -> scratch spill (60-490MB scratch writes).
// Fix: KEEP the barrier skeleton (bounds the scheduler, no spill), but
// issue next-slot loads AFTER the barrier: drain becomes a no-op and loads
// cover the whole slot's compute. 2 rows per slot halves barrier count and
// doubles the cover window. In-slot order HA->VA->HB->VB so row 2t+1's
// horizontal sums don't evict row 2t-10 before its vertical pass.
extern "C" __global__ __launch_bounds__(512) void ssim_structure_kernel(
    const float* __restrict__ x, const float* __restrict__ y,
    float* __restrict__ accum, unsigned int* __restrict__ counter,
    float* __restrict__ out) {
  const int tid = threadIdx.x;
  const int band = blockIdx.x;   // 0..31
  const int plane = blockIdx.y;  // 0..23

  const size_t pbase = (size_t)plane * IMG_H * IMG_W;
  const float* __restrict__ xp = x + pbase;
  const float* __restrict__ yp = y + pbase;
  const int r0 = band * ROWS_PER_BLK;

  // staged rows: index j holds image col j-5 (522 used, pad to 528)
  // [sel][rowA/rowB][col]
  __shared__ f32x2 lrow[2][2][528];

  // circular register buffers of horizontal sums (1 col/thread)
  f32x2 bm[11];   // (Swx,  Swy)
  f32x2 bq[11];   // (Swxx, Swyy)
  float bxy[11];  // Swxy

  // ---- branch-free column addressing (mask applied at STAGE time) ----
  const int gc = tid - 5;                       // main col
  const int gcc = min(max(gc, 0), IMG_W - 1);
  const float cmask = (gc >= 0 && gc < IMG_W) ? 1.0f : 0.0f;
  const int gc2 = tid + 507;                    // halo col (lanes 0..9)
  const int gc2c = min(gc2, IMG_W - 1);
  const float hmask = (gc2 < IMG_W) ? 1.0f : 0.0f;

  f32x2 pAm = {0.f, 0.f}, pAe = {0.f, 0.f};
  f32x2 pBm = {0.f, 0.f}, pBe = {0.f, 0.f};

  float acc = 0.0f;

  auto loadrow = [&](int i, f32x2& m, f32x2& e) {
    const int hr = r0 - 5 + i;
    if ((i < NROWS) && (hr >= 0) && (hr < IMG_H)) {  // wave-uniform
      const int ro = hr * IMG_W;
      f32x2 v;
      v.x = xp[ro + gcc];
      v.y = yp[ro + gcc];
      m = v;
      if (tid < 10) {
        f32x2 h;
        h.x = xp[ro + gc2c];
        h.y = yp[ro + gc2c];
        e = h;
      }
    } else {
      m = (f32x2){0.f, 0.f};
      e = (f32x2){0.f, 0.f};
    }
  };

  auto stage = [&](f32x2* dst, const f32x2 m, const f32x2 e) {
    dst[tid] = m * cmask;
    if (tid < 10) dst[512 + tid] = e * hmask;
  };

  auto horiz = [&](const f32x2* src, int ii) {  // ii compile-time
    f32x2 tm = {0.f, 0.f};
    f32x2 tq = {0.f, 0.f};
    float txy = 0.f;
#pragma unroll
    for (int d = 0; d < 11; ++d) {
      const f32x2 v = src[tid + d];
      const float wgt = GWc[d];
      const f32x2 wv = v * wgt;
      tm += wv;
      tq = __builtin_elementwise_fma(wv, v, tq);
      txy = fmaf(wv.x, v.y, txy);
    }
    bm[ii] = tm;
    bq[ii] = tq;
    bxy[ii] = txy;
  };

  auto vert = [&](int ii) {  // ii compile-time; output row = staged row - 10
    f32x2 vm = {0.f, 0.f};
    f32x2 vq = {0.f, 0.f};
    float vxy = 0.f;
#pragma unroll
    for (int k = 0; k < 11; ++k) {
      const int s2 = (ii + 1 + k) % 11;  // compile-time
      const float wgt = GWc[k];
      const f32x2 w2 = {wgt, wgt};
      vm = __builtin_elementwise_fma(bm[s2], w2, vm);
      vq = __builtin_elementwise_fma(bq[s2], w2, vq);
      vxy = fmaf(wgt, bxy[s2], vxy);
    }
    const float sxy = fmaf(-vm.x, vm.y, vxy);
    f32x2 sp = __builtin_elementwise_fma(-vm, vm, vq);
    sp = __builtin_elementwise_max(sp, (f32x2){1e-12f, 1e-12f});
    const float den = sqrtf(sp.x * sp.y) + 1e-4f;
    acc = fmaf(sxy + 1e-4f, __builtin_amdgcn_rcpf(den), acc);
  };

  // prologue: rows 0,1 in flight; consumed at first stage
  loadrow(0, pAm, pAe);
  loadrow(1, pBm, pBe);

#pragma unroll
  for (int t = 0; t < NSLOTS; ++t) {
    const int sel = t & 1;            // compile-time
    const int iiA = (2 * t) % 11;     // compile-time
    const int iiB = (2 * t + 1) % 11; // compile-time

    // stage rows 2t, 2t+1 (counted vmcnt wait on the slot-(t-1) issue)
    stage(lrow[sel][0], pAm, pAe);
    stage(lrow[sel][1], pBm, pBe);

    __syncthreads();  // nothing in flight here -> the vmcnt(0) drain is free

    // issue next slot's loads NOW; they fly across this slot's compute
    loadrow(2 * t + 2, pAm, pAe);
    loadrow(2 * t + 3, pBm, pBe);

    // HA -> VA -> HB -> VB (VA must precede HB: HB evicts row 2t-10's sums)
    horiz(lrow[sel][0], iiA);
    if (t >= 5) vert(iiA);            // output row 2t-10
    horiz(lrow[sel][1], iiB);
    if (t >= 5) vert(iiB);            // output row 2t-9
  }

  // ---- block reduction: wave shuffle then cross-wave LDS ----
#pragma unroll
  for (int off = 32; off > 0; off >>= 1) acc += __shfl_down(acc, off, 64);
  __shared__ float wsum[8];
  if ((tid & 63) == 0) wsum[tid >> 6] = acc;
  __syncthreads();
  if (tid == 0) {
    float bsum = 0.f;
#pragma unroll
    for (int v = 0; v < 8; ++v) bsum += wsum[v];
    atomicAdd(accum, bsum);
    __threadfence();
    const unsigned int ret = atomicAdd(counter, 1u);
    if (ret == (unsigned int)(NBLOCKS - 1)) {
      // all blocks' accum atomics are fenced-before their counter atomics,
      // so the running total is complete; atomic read bypasses stale caches
      __threadfence();
      const float total = atomicAdd(accum, 0.0f);
      out[0] = 1.0f - total * (1.0f / TOTAL_PIX);
    }
  }
}

extern "C" void kernel_launch(void* const* d_in, const int* in_sizes, int n_in,
                              void* d_out, int out_size, void* d_ws,
                              size_t ws_size, hipStream_t stream) {
  const float* x = (const float*)d_in[0];
  const float* y = (const float*)d_in[1];
  float* out = (float*)d_out;
  float* accum = (float*)d_ws;
  unsigned int* counter = (unsigned int*)((char*)d_ws + sizeof(float));

  hipMemsetAsync(d_ws, 0, 2 * sizeof(float), stream);

  dim3 grid(IMG_H / ROWS_PER_BLK, NPLANES);  // 32 x 24 = 768 blocks
  ssim_structure_kernel<<<grid, 512, 0, stream>>>(x, y, accum, counter, out);
}

// Round 9
// 137.370 us; speedup vs baseline: 2.7459x; 2.7459x over previous
//
#include <hip/hip_runtime.h>

#define IMG_H 512
#define IMG_W 512
#define NPLANES 24          // N*C = 8*3
#define ROWS_PER_BLK 16     // output rows per block
#define NITER 26            // staged rows per block (16 + 10 halo)
#define NBLOCKS (32 * 24)
#define TOTAL_PIX 6291456.0f // 8*3*512*512

typedef float f32x2 __attribute__((ext_vector_type(2)));

// Gaussian window, sigma=1.5, K=11, normalized (matches jnp reference ~1e-7)
constexpr float GWc[11] = {
    0.00102838f, 0.00759876f, 0.03600050f, 0.10935817f, 0.21300535f,
    0.26601172f, 0.21300535f, 0.10935817f, 0.03600050f, 0.00759876f,
    0.00102838f};

// Round 9. Accumulated evidence:
//  - FULL loop unroll (R7/R8) => scheduler pipelines across slot bodies,
//    live ranges explode, 128 VGPR cap + x00MB scratch. Runtime outer loop
//    (R0-R3) => 44-52 VGPR, no scratch. KEEP THE RUNTIME OUTER LOOP.
//  - In R0-R3 the next-row loads were issued BEFORE __syncthreads, whose
//    implicit s_waitcnt vmcnt(0) drains them => prefetch depth was
//    effectively ZERO; every slot exposed full HBM latency. That is the
//    invariant ~75us wall (VALU-busy only ~27-39us).
// This round's single structural change: issue the loads AFTER the barrier,
// so they fly across the slot's horizontal+vertical compute and the counted
// wait lands at the next slot's LDS stage.
// Simplification: full-row strips make the column halo out-of-image ->
// zero the 5 pad cols per side ONCE; hot loop has no masks/clamps/divergent
// halo loads, and the global load is a clean coalesced pair at col=tid.
extern "C" __global__ __launch_bounds__(512) void ssim_structure_kernel(
    const float* __restrict__ x, const float* __restrict__ y,
    float* __restrict__ accum, unsigned int* __restrict__ counter,
    float* __restrict__ out) {
  const int tid = threadIdx.x;
  const int band = blockIdx.x;   // 0..31
  const int plane = blockIdx.y;  // 0..23

  const size_t pbase = (size_t)plane * IMG_H * IMG_W;
  const float* __restrict__ xp = x + pbase;
  const float* __restrict__ yp = y + pbase;
  const int r0 = band * ROWS_PER_BLK;

  // double-buffered staging row: LDS col j holds image col j-5
  // (522 used, pad to 528). (x,y) interleaved -> ds_*_b64, conflict-free.
  __shared__ f32x2 lrow[2][528];

  // zero the out-of-image pad columns once (cols -5..-1 and 512..516);
  // ordered before any read by the first in-loop barrier
  if (tid < 20) {
    const int b = tid / 10, k = tid % 10;
    lrow[b][(k < 5) ? k : (512 + k)] = (f32x2){0.f, 0.f};
  }

  // circular register buffers of horizontal sums (1 col/thread)
  f32x2 bm[11];   // (Swx,  Swy)
  f32x2 bq[11];   // (Swxx, Swyy)
  float bxy[11];  // Swxy

  f32x2 pre = {0.f, 0.f};
  float acc = 0.0f;

  auto loadrow = [&](int i, f32x2& v) {
    const int hr = r0 - 5 + i;
    if ((i < NITER) && (hr >= 0) && (hr < IMG_H)) {  // wave-uniform branch
      const int ro = hr * IMG_W + tid;
      v.x = xp[ro];
      v.y = yp[ro];
    } else {
      v = (f32x2){0.f, 0.f};
    }
  };

  loadrow(0, pre);

  for (int ob = 0; ob < 3; ++ob) {  // runtime outer loop: bounds register
                                    // pressure (R7/R8 full-unroll spilled)
#pragma unroll
    for (int ii = 0; ii < 11; ++ii) {
      const int i = ob * 11 + ii;
      if (i < NITER) {
        const int sel = i & 1;

        // stage row i (counted vmcnt wait on loads issued last slot, which
        // had a full slot of compute to fly)
        lrow[sel][tid + 5] = pre;

        __syncthreads();  // nothing in flight -> implicit vmcnt drain free

        // issue row i+1 loads NOW: they cover this slot's compute
        loadrow(i + 1, pre);

        // ---- horizontal pass -> circular slot ii (== i % 11) ----
        {
          f32x2 tm = {0.f, 0.f};
          f32x2 tq = {0.f, 0.f};
          float txy = 0.f;
#pragma unroll
          for (int d = 0; d < 11; ++d) {
            const f32x2 v = lrow[sel][tid + d];
            const float wgt = GWc[d];
            const f32x2 wv = v * wgt;
            tm += wv;
            tq = __builtin_elementwise_fma(wv, v, tq);
            txy = fmaf(wv.x, v.y, txy);
          }
          bm[ii] = tm;
          bq[ii] = tq;
          bxy[ii] = txy;
        }

        // ---- vertical pass + epilogue for output row r0 + (i - 10) ----
        if (i >= 10) {
          f32x2 vm = {0.f, 0.f};
          f32x2 vq = {0.f, 0.f};
          float vxy = 0.f;
#pragma unroll
          for (int k = 0; k < 11; ++k) {
            const int s2 = (ii + 1 + k) % 11;  // compile-time after unroll
            const float wgt = GWc[k];
            const f32x2 w2 = {wgt, wgt};
            vm = __builtin_elementwise_fma(bm[s2], w2, vm);
            vq = __builtin_elementwise_fma(bq[s2], w2, vq);
            vxy = fmaf(wgt, bxy[s2], vxy);
          }
          const float sxy = fmaf(-vm.x, vm.y, vxy);
          f32x2 sp = __builtin_elementwise_fma(-vm, vm, vq);
          sp = __builtin_elementwise_max(sp, (f32x2){1e-12f, 1e-12f});
          const float den = sqrtf(sp.x * sp.y) + 1e-4f;
          acc = fmaf(sxy + 1e-4f, __builtin_amdgcn_rcpf(den), acc);
        }
      }
    }
  }

  // ---- block reduction: wave shuffle then cross-wave LDS ----
#pragma unroll
  for (int off = 32; off > 0; off >>= 1) acc += __shfl_down(acc, off, 64);
  __shared__ float wsum[8];
  if ((tid & 63) == 0) wsum[tid >> 6] = acc;
  __syncthreads();
  if (tid == 0) {
    float bsum = 0.f;
#pragma unroll
    for (int v = 0; v < 8; ++v) bsum += wsum[v];
    atomicAdd(accum, bsum);
    __threadfence();
    const unsigned int ret = atomicAdd(counter, 1u);
    if (ret == (unsigned int)(NBLOCKS - 1)) {
      // all blocks' accum atomics are fenced-before their counter atomics,
      // so the running total is complete; atomic read bypasses stale caches
      __threadfence();
      const float total = atomicAdd(accum, 0.0f);
      out[0] = 1.0f - total * (1.0f / TOTAL_PIX);
    }
  }
}

extern "C" void kernel_launch(void* const* d_in, const int* in_sizes, int n_in,
                              void* d_out, int out_size, void* d_ws,
                              size_t ws_size, hipStream_t stream) {
  const float* x = (const float*)d_in[0];
  const float* y = (const float*)d_in[1];
  float* out = (float*)d_out;
  float* accum = (float*)d_ws;
  unsigned int* counter = (unsigned int*)((char*)d_ws + sizeof(float));

  hipMemsetAsync(d_ws, 0, 2 * sizeof(float), stream);

  dim3 grid(IMG_H / ROWS_PER_BLK, NPLANES);  // 32 x 24 = 768 blocks
  ssim_structure_kernel<<<grid, 512, 0, stream>>>(x, y, accum, counter, out);
}